// Round 2
// baseline (637.221 us; speedup 1.0000x reference)
//
#include <hip/hip_runtime.h>
#include <hip/hip_bf16.h>
#include <stdint.h>

// Problem dims (JointNetwork): B=4, T=512, U=100, A_FEAT=512, TXT_FEAT=320, HID=640, NCLS=512
// Inputs/outputs are FLOAT32 (per reference). Internal compute: bf16 MFMA, f32 accumulate.
#define BB   4
#define TT   512
#define UU   100
#define AF   512
#define TXF  320
#define HID  640
#define NCLS 512
#define TU   (TT * UU)   // 51200
#define M3   (BB * TU)   // 204800

typedef unsigned short ushort_t;
typedef __attribute__((ext_vector_type(8))) short frag_ab;           // 8 bf16 = 4 VGPRs (MFMA A/B)
typedef __attribute__((ext_vector_type(4))) float frag_cd;           // 4 f32 accum
typedef __attribute__((ext_vector_type(8))) unsigned short ushort8;  // 16B pack

__device__ __forceinline__ float bf2f(unsigned short h) {
    return __uint_as_float(((unsigned)h) << 16);
}
__device__ __forceinline__ unsigned short f2bf(float f) {
    unsigned u = __float_as_uint(f);
    u += 0x7FFFu + ((u >> 16) & 1u);   // round-to-nearest-even
    return (unsigned short)(u >> 16);
}
// tanh(x) = 1 - 2/(e^{2x}+1); saturates correctly at +-inf. ~1e-5 accuracy, plenty here.
__device__ __forceinline__ float tanh_fast(float x) {
    float e = __expf(2.0f * x);
    return 1.0f - 2.0f * __builtin_amdgcn_rcpf(e + 1.0f);
}

// ---------------- weight transpose+cast (f32 [K][N] -> bf16 [N][K]) ----------------
__global__ void tcast_kernel(const float* __restrict__ src, ushort_t* __restrict__ dst,
                             int K, int N) {
    int i = blockIdx.x * 256 + threadIdx.x;
    if (i >= K * N) return;
    int k = i / N;
    int n = i - k * N;
    dst[n * K + k] = f2bf(src[i]);
}

// ---------------- projection GEMM: P[M][HID] = X[M][K] @ W[K][HID] + bias, bf16 out ----------------
// X is f32; Wt is pre-transposed bf16 [HID][K]; bias f32; P bf16.
// 128x128 tile, 4 waves (2x2), 16x16x32 bf16 MFMA, BK=64.
__global__ __launch_bounds__(256) void proj_kernel(
    const float* __restrict__ X, const ushort_t* __restrict__ Wt,
    const float* __restrict__ bias, ushort_t* __restrict__ P,
    int M, int K)
{
    __shared__ ushort_t As[128][72];   // +8 pad; rows are 144B = 16B-aligned
    __shared__ ushort_t Bs[128][72];
    int tid = threadIdx.x;
    int m0 = blockIdx.x * 128, n0 = blockIdx.y * 128;
    int wave = tid >> 6, lane = tid & 63;
    int wr = (wave >> 1) * 64, wc = (wave & 1) * 64;
    int lm = lane & 15, lq = lane >> 4;
    frag_cd acc[4][4];
    #pragma unroll
    for (int i = 0; i < 4; ++i)
        #pragma unroll
        for (int j = 0; j < 4; ++j) { frag_cd z = {0.f, 0.f, 0.f, 0.f}; acc[i][j] = z; }
    int rs = tid >> 3, k8 = tid & 7;

    for (int k0 = 0; k0 < K; k0 += 64) {
        #pragma unroll
        for (int it = 0; it < 4; ++it) {
            int r = rs + it * 32;
            int m = m0 + r;
            float4 v0 = make_float4(0.f, 0.f, 0.f, 0.f), v1 = v0;
            if (m < M) {
                const float* xp = X + (size_t)m * K + (k0 + k8 * 8);
                v0 = *(const float4*)xp;
                v1 = *(const float4*)(xp + 4);
            }
            ushort8 o;
            o[0] = f2bf(v0.x); o[1] = f2bf(v0.y); o[2] = f2bf(v0.z); o[3] = f2bf(v0.w);
            o[4] = f2bf(v1.x); o[5] = f2bf(v1.y); o[6] = f2bf(v1.z); o[7] = f2bf(v1.w);
            *(ushort8*)&As[r][k8 * 8] = o;
            uint4 w = *(const uint4*)(Wt + (size_t)(n0 + r) * K + (k0 + k8 * 8));
            *(uint4*)&Bs[r][k8 * 8] = w;
        }
        __syncthreads();
        #pragma unroll
        for (int kk = 0; kk < 64; kk += 32) {
            frag_ab af[4], bfr[4];
            #pragma unroll
            for (int i = 0; i < 4; ++i) af[i]  = *(const frag_ab*)&As[wr + i * 16 + lm][kk + lq * 8];
            #pragma unroll
            for (int j = 0; j < 4; ++j) bfr[j] = *(const frag_ab*)&Bs[wc + j * 16 + lm][kk + lq * 8];
            #pragma unroll
            for (int i = 0; i < 4; ++i)
                #pragma unroll
                for (int j = 0; j < 4; ++j)
                    acc[i][j] = __builtin_amdgcn_mfma_f32_16x16x32_bf16(af[i], bfr[j], acc[i][j], 0, 0, 0);
        }
        __syncthreads();
    }
    // epilogue: C/D layout col=lane&15, row=(lane>>4)*4+reg (m89-verified)
    #pragma unroll
    for (int j = 0; j < 4; ++j) {
        int n = n0 + wc + j * 16 + lm;
        float bv = bias[n];
        #pragma unroll
        for (int i = 0; i < 4; ++i) {
            int mb = m0 + wr + i * 16 + lq * 4;
            #pragma unroll
            for (int r = 0; r < 4; ++r) {
                int m = mb + r;
                if (m < M) P[(size_t)m * HID + n] = f2bf(acc[i][j][r] + bv);
            }
        }
    }
}

// ---------------- fused joint: out[m][v] = tanh(a[b,ti,:] + t[b,ui,:]) @ Wj + bj ----------------
// Block = 128 rows x 256 cols; 4 waves as 2x2 (wave tile 64x128).
// A-tile generated on the fly (bf16 add + tanh -> bf16); B from pre-transposed bf16 Wtj[NCLS][HID].
// Output f32, bias f32.
__global__ __launch_bounds__(256, 2) void joint_kernel(
    const ushort_t* __restrict__ Pa, const ushort_t* __restrict__ Pt,
    const ushort_t* __restrict__ Wtj, const float* __restrict__ bj,
    float* __restrict__ out)
{
    __shared__ ushort_t As[128][72];
    __shared__ ushort_t Bs[256][72];
    __shared__ int aOff[128];
    __shared__ int tOff[128];
    int tid = threadIdx.x;
    int m0 = blockIdx.x * 128;
    int n0 = blockIdx.y * 256;
    if (tid < 128) {
        int m  = m0 + tid;
        int b  = m / TU;
        int rb = m - b * TU;
        int ti = rb / UU;
        int ui = rb - ti * UU;
        aOff[tid] = (b * TT + ti) * HID;
        tOff[tid] = (b * UU + ui) * HID;
    }
    int wave = tid >> 6, lane = tid & 63;
    int wr = (wave >> 1) * 64;       // row offset of wave tile
    int wc = (wave & 1) * 128;       // col offset of wave tile
    int lm = lane & 15, lq = lane >> 4;
    frag_cd acc[4][8];
    #pragma unroll
    for (int i = 0; i < 4; ++i)
        #pragma unroll
        for (int j = 0; j < 8; ++j) { frag_cd z = {0.f, 0.f, 0.f, 0.f}; acc[i][j] = z; }
    int rs = tid >> 3, k8 = tid & 7;
    __syncthreads();

    for (int k0 = 0; k0 < HID; k0 += 64) {
        // generate A tile: tanh(a + t), 32 elems/thread
        #pragma unroll
        for (int it = 0; it < 4; ++it) {
            int r = rs + it * 32;
            const ushort_t* ap = Pa + aOff[r] + k0 + k8 * 8;
            const ushort_t* tp = Pt + tOff[r] + k0 + k8 * 8;
            uint4 av = *(const uint4*)ap;
            uint4 tv = *(const uint4*)tp;
            const unsigned* au = (const unsigned*)&av;
            const unsigned* tu = (const unsigned*)&tv;
            ushort8 o;
            #pragma unroll
            for (int j = 0; j < 4; ++j) {
                unsigned ua = au[j], ut = tu[j];
                float s0 = __uint_as_float(ua << 16) + __uint_as_float(ut << 16);
                float s1 = __uint_as_float(ua & 0xFFFF0000u) + __uint_as_float(ut & 0xFFFF0000u);
                o[2 * j]     = f2bf(tanh_fast(s0));
                o[2 * j + 1] = f2bf(tanh_fast(s1));
            }
            *(ushort8*)&As[r][k8 * 8] = o;
        }
        // stage B tile (256 rows of Wtj)
        #pragma unroll
        for (int it = 0; it < 8; ++it) {
            int r = rs + it * 32;
            *(uint4*)&Bs[r][k8 * 8] = *(const uint4*)(Wtj + (size_t)(n0 + r) * HID + k0 + k8 * 8);
        }
        __syncthreads();
        #pragma unroll
        for (int kk = 0; kk < 64; kk += 32) {
            frag_ab af[4], bfr[8];
            #pragma unroll
            for (int i = 0; i < 4; ++i) af[i]  = *(const frag_ab*)&As[wr + i * 16 + lm][kk + lq * 8];
            #pragma unroll
            for (int j = 0; j < 8; ++j) bfr[j] = *(const frag_ab*)&Bs[wc + j * 16 + lm][kk + lq * 8];
            #pragma unroll
            for (int i = 0; i < 4; ++i)
                #pragma unroll
                for (int j = 0; j < 8; ++j)
                    acc[i][j] = __builtin_amdgcn_mfma_f32_16x16x32_bf16(af[i], bfr[j], acc[i][j], 0, 0, 0);
        }
        __syncthreads();
    }
    // epilogue: add bj, f32 store. out flat index = m*NCLS + n.
    #pragma unroll
    for (int j = 0; j < 8; ++j) {
        int n = n0 + wc + j * 16 + lm;
        float bv = bj[n];
        #pragma unroll
        for (int i = 0; i < 4; ++i) {
            size_t mb = (size_t)(m0 + wr + i * 16 + lq * 4);
            #pragma unroll
            for (int r = 0; r < 4; ++r) {
                out[(mb + r) * (size_t)NCLS + n] = acc[i][j][r] + bv;
            }
        }
    }
}

extern "C" void kernel_launch(void* const* d_in, const int* in_sizes, int n_in,
                              void* d_out, int out_size, void* d_ws, size_t ws_size,
                              hipStream_t stream)
{
    const float* audio = (const float*)d_in[0];  // [4,512,512] f32
    const float* text  = (const float*)d_in[1];  // [4,100,320] f32
    const float* Wa    = (const float*)d_in[2];  // [512,640]
    const float* ba    = (const float*)d_in[3];  // [640]
    const float* Wt    = (const float*)d_in[4];  // [320,640]
    const float* bt    = (const float*)d_in[5];  // [640]
    const float* Wj    = (const float*)d_in[6];  // [640,512]
    const float* bjv   = (const float*)d_in[7];  // [512]
    float* out = (float*)d_out;

    char* ws = (char*)d_ws;
    // ws layout (bytes, all bf16): Pa 2621440 | Pt 512000 | Wta 655360 | Wtt 409600 | Wtj 655360
    ushort_t* Pa  = (ushort_t*)(ws);
    ushort_t* Pt  = (ushort_t*)(ws + 2621440);
    ushort_t* Wta = (ushort_t*)(ws + 3133440);
    ushort_t* Wtt = (ushort_t*)(ws + 3788800);
    ushort_t* Wtj = (ushort_t*)(ws + 4198400);

    // weight transposes+casts: W[K][N] f32 -> Wt[N][K] bf16
    tcast_kernel<<<dim3((AF * HID + 255) / 256), 256, 0, stream>>>(Wa, Wta, AF, HID);
    tcast_kernel<<<dim3((TXF * HID + 255) / 256), 256, 0, stream>>>(Wt, Wtt, TXF, HID);
    tcast_kernel<<<dim3((HID * NCLS + 255) / 256), 256, 0, stream>>>(Wj, Wtj, HID, NCLS);

    // projections: a = audio@Wa + ba (M=2048, K=512), t = text@Wt + bt (M=400, K=320)
    proj_kernel<<<dim3(16, 5), 256, 0, stream>>>(audio, Wta, ba, Pa, BB * TT, AF);
    proj_kernel<<<dim3(4, 5), 256, 0, stream>>>(text, Wtt, bt, Pt, BB * UU, TXF);

    // fused tanh + final GEMM: [204800 x 640] @ [640 x 512] -> f32 out
    joint_kernel<<<dim3(M3 / 128, NCLS / 256), 256, 0, stream>>>(Pa, Pt, Wtj, bjv, out);
}